// Round 3
// baseline (669.313 us; speedup 1.0000x reference)
//
#include <hip/hip_runtime.h>
#include <math.h>

// Problem constants: N=500000, NFEAT=64, K=8, HK=64
constexpr int NS  = 500000;
constexpr int NF  = 64;
constexpr int KG  = 8;
constexpr int HKC = 64;

typedef __attribute__((ext_vector_type(8))) _Float16 half8;
typedef __attribute__((ext_vector_type(4))) float f32x4;

// ---- DPP row_ror helpers (rotate within each 16-lane row; VALU pipe, no LDS) ----
template <int CTRL>
__device__ __forceinline__ float row_ror_f(float v) {
    int i = __float_as_int(v);
    int r = __builtin_amdgcn_update_dpp(i, i, CTRL, 0xF, 0xF, false);
    return __int_as_float(r);
}
template <int CTRL>
__device__ __forceinline__ unsigned row_ror_u(unsigned v) {
    return (unsigned)__builtin_amdgcn_update_dpp((int)v, (int)v, CTRL, 0xF, 0xF, false);
}
// full 16-lane max: after ror 1,2,4,8 every lane holds the row-wide max
__device__ __forceinline__ float row_max16(float v) {
    v = fmaxf(v, row_ror_f<0x121>(v));  // row_ror:1
    v = fmaxf(v, row_ror_f<0x122>(v));  // row_ror:2
    v = fmaxf(v, row_ror_f<0x124>(v));  // row_ror:4
    v = fmaxf(v, row_ror_f<0x128>(v));  // row_ror:8
    return v;
}
__device__ __forceinline__ unsigned row_min16_u(unsigned v) {
    v = min(v, row_ror_u<0x121>(v));
    v = min(v, row_ror_u<0x122>(v));
    v = min(v, row_ror_u<0x124>(v));
    v = min(v, row_ror_u<0x128>(v));
    return v;
}

// Kernel 1: w = exp(z) (fp32) split into fp16 hi/lo pair; zero the A region.
__global__ void prep_kernel(const float* __restrict__ z,
                            _Float16* __restrict__ w_hi,
                            _Float16* __restrict__ w_lo,
                            float* __restrict__ A) {
    int i = blockIdx.x * blockDim.x + threadIdx.x;
    if (i < KG * HKC * NF) {
        float w = expf(z[i]);
        _Float16 h = (_Float16)w;           // RNE
        w_hi[i] = h;
        w_lo[i] = (_Float16)(w - (float)h); // residual: ~2^-22 total pair error
    }
    if (i < KG * HKC) A[i] = 0.0f;
}

// Main kernel: one wave handles 32 rows (2 MFMA row-tiles), all 512 cols.
// Groups processed sequentially -> only 32 acc VGPRs live at a time.
// Fragment layouts (measured, learn_hip m89/m120):
//   A: A[m = lane&15][k = (lane>>4)*8 + j]   (w is [col][k] = B^T, loads identically)
//   C: col = lane&15, row = (lane>>4)*4 + reg
__global__ __launch_bounds__(256, 4) void monn_mfma_kernel(
    const float* __restrict__ x,
    const _Float16* __restrict__ w_hi,
    const _Float16* __restrict__ w_lo,
    const float* __restrict__ t,
    float* __restrict__ y,
    float* __restrict__ A) {

    const int lane = threadIdx.x & 63;
    const int wave = blockIdx.x * 4 + (threadIdx.x >> 6);
    const int base = wave * 32;
    if (base >= NS) return;           // whole-wave exit (500000/32 = 15625 exact)

    const int m = lane & 15;
    const int q = lane >> 4;

    // --- Load x rows and split to fp16 hi/lo fragments (x read exactly once) ---
    half8 Ah[2][2], Al[2][2];
#pragma unroll
    for (int rt = 0; rt < 2; ++rt) {
        const float* xp = x + (size_t)(base + rt * 16 + m) * NF;
#pragma unroll
        for (int s = 0; s < 2; ++s) {
            const int k0 = s * 32 + q * 8;
            const float4 v0 = *reinterpret_cast<const float4*>(xp + k0);
            const float4 v1 = *reinterpret_cast<const float4*>(xp + k0 + 4);
            const float xv[8] = {v0.x, v0.y, v0.z, v0.w, v1.x, v1.y, v1.z, v1.w};
#pragma unroll
            for (int j = 0; j < 8; ++j) {
                _Float16 h = (_Float16)xv[j];
                Ah[rt][s][j] = h;
                Al[rt][s][j] = (_Float16)(xv[j] - (float)h);
            }
        }
    }

    float    ymin[2][4];
    unsigned code[2][4];
#pragma unroll
    for (int rt = 0; rt < 2; ++rt)
#pragma unroll
        for (int j = 0; j < 4; ++j) { ymin[rt][j] = INFINITY; code[rt][j] = 0; }

    for (int g = 0; g < KG; ++g) {
        f32x4 acc[2][4];
        // fold bias t into accumulator init: all 4 regs of a lane share col c*16+m
#pragma unroll
        for (int c = 0; c < 4; ++c) {
            const float tv = t[g * HKC + c * 16 + m];
            acc[0][c] = (f32x4){tv, tv, tv, tv};
            acc[1][c] = acc[0][c];
        }
#pragma unroll
        for (int c = 0; c < 4; ++c) {
            const _Float16* bph = w_hi + (size_t)(g * HKC + c * 16 + m) * NF;
            const _Float16* bpl = w_lo + (size_t)(g * HKC + c * 16 + m) * NF;
#pragma unroll
            for (int s = 0; s < 2; ++s) {
                const half8 Bh = *reinterpret_cast<const half8*>(bph + s * 32 + q * 8);
                const half8 Bl = *reinterpret_cast<const half8*>(bpl + s * 32 + q * 8);
#pragma unroll
                for (int rt = 0; rt < 2; ++rt) {
                    acc[rt][c] = __builtin_amdgcn_mfma_f32_16x16x32_f16(Ah[rt][s], Bh, acc[rt][c], 0, 0, 0);
                    acc[rt][c] = __builtin_amdgcn_mfma_f32_16x16x32_f16(Al[rt][s], Bh, acc[rt][c], 0, 0, 0);
                    acc[rt][c] = __builtin_amdgcn_mfma_f32_16x16x32_f16(Ah[rt][s], Bl, acc[rt][c], 0, 0, 0);
                }
            }
        }

        // --- epilogue: per row, argmax over this group's 64 cols, then running min.
        // All-VALU: DPP rotate-reduce (no ds_swizzle / lgkmcnt chains).
#pragma unroll
        for (int rt = 0; rt < 2; ++rt) {
#pragma unroll
            for (int j = 0; j < 4; ++j) {
                // value max: 4 in-lane (cols c*16+m), then 16-lane DPP reduce
                float vloc = fmaxf(fmaxf(acc[rt][0][j], acc[rt][1][j]),
                                   fmaxf(acc[rt][2][j], acc[rt][3][j]));
                const float vmax = row_max16(vloc);
                // argmax by equality: smallest h in-lane (descending c keeps first),
                // then 16-lane min of h codes -> first-occurrence jnp.argmax semantics
                unsigned h = 0x7FFFFFFFu;
#pragma unroll
                for (int c = 3; c >= 0; --c)
                    h = (acc[rt][c][j] == vmax) ? (unsigned)(c * 16 + m) : h;
                h = row_min16_u(h);
                // running min over groups: strict < keeps first (lowest g)
                if (vmax < ymin[rt][j]) { ymin[rt][j] = vmax; code[rt][j] = (unsigned)(g * HKC) + h; }
            }
        }
    }

    // one lane per 4 rows writes y and bumps the histogram
    if (m == 0) {
#pragma unroll
        for (int rt = 0; rt < 2; ++rt)
#pragma unroll
            for (int j = 0; j < 4; ++j) {
                const int row = base + rt * 16 + q * 4 + j;
                y[row] = ymin[rt][j];
                atomicAdd(&A[code[rt][j]], 1.0f);  // device-scope by default
            }
    }
}

extern "C" void kernel_launch(void* const* d_in, const int* in_sizes, int n_in,
                              void* d_out, int out_size, void* d_ws, size_t ws_size,
                              hipStream_t stream) {
    const float* x = (const float*)d_in[0];  // [NS, NF]
    const float* z = (const float*)d_in[1];  // [KG, HKC, NF]
    const float* t = (const float*)d_in[2];  // [KG, HKC]

    float* y = (float*)d_out;        // [NS]
    float* A = (float*)d_out + NS;   // [KG*HKC]

    _Float16* w_hi = (_Float16*)d_ws;                 // 64 KB
    _Float16* w_lo = w_hi + (size_t)KG * HKC * NF;    // 64 KB

    const int prep_elems = KG * HKC * NF;
    prep_kernel<<<(prep_elems + 255) / 256, 256, 0, stream>>>(z, w_hi, w_lo, A);

    const int waves = NS / 32;                  // 15625
    const int blocks = (waves + 3) / 4;         // 3907
    monn_mfma_kernel<<<blocks, 256, 0, stream>>>(x, w_hi, w_lo, t, y, A);
}

// Round 4
// 628.148 us; speedup vs baseline: 1.0655x; 1.0655x over previous
//
#include <hip/hip_runtime.h>
#include <math.h>

// Problem constants: N=500000, NFEAT=64, K=8, HK=64
constexpr int NS  = 500000;
constexpr int NF  = 64;
constexpr int KG  = 8;
constexpr int HKC = 64;

typedef __attribute__((ext_vector_type(8))) _Float16 half8;
typedef __attribute__((ext_vector_type(4))) float f32x4;

// ---- DPP row_ror helpers (rotate within each 16-lane row; VALU pipe, no LDS) ----
template <int CTRL>
__device__ __forceinline__ float row_ror_f(float v) {
    int i = __float_as_int(v);
    int r = __builtin_amdgcn_update_dpp(i, i, CTRL, 0xF, 0xF, false);
    return __int_as_float(r);
}
template <int CTRL>
__device__ __forceinline__ unsigned row_ror_u(unsigned v) {
    return (unsigned)__builtin_amdgcn_update_dpp((int)v, (int)v, CTRL, 0xF, 0xF, false);
}
__device__ __forceinline__ float row_max16(float v) {
    v = fmaxf(v, row_ror_f<0x121>(v));  // row_ror:1
    v = fmaxf(v, row_ror_f<0x122>(v));  // row_ror:2
    v = fmaxf(v, row_ror_f<0x124>(v));  // row_ror:4
    v = fmaxf(v, row_ror_f<0x128>(v));  // row_ror:8
    return v;
}
__device__ __forceinline__ unsigned row_min16_u(unsigned v) {
    v = min(v, row_ror_u<0x121>(v));
    v = min(v, row_ror_u<0x122>(v));
    v = min(v, row_ror_u<0x124>(v));
    v = min(v, row_ror_u<0x128>(v));
    return v;
}

// Kernel 1: w = exp(z) (fp32) split into fp16 hi/lo pair; zero the A region.
__global__ void prep_kernel(const float* __restrict__ z,
                            _Float16* __restrict__ w_hi,
                            _Float16* __restrict__ w_lo,
                            float* __restrict__ A) {
    int i = blockIdx.x * blockDim.x + threadIdx.x;
    if (i < KG * HKC * NF) {
        float w = expf(z[i]);
        _Float16 h = (_Float16)w;           // RNE
        w_hi[i] = h;
        w_lo[i] = (_Float16)(w - (float)h); // residual: ~2^-22 total pair error
    }
    if (i < KG * HKC) A[i] = 0.0f;
}

// Main kernel: one wave handles 64 rows (4 MFMA row-tiles), all 512 cols.
// __launch_bounds__(256,2): 256-VGPR budget — A frags (64) + acc (64, AGPR) +
// B batch (32) + ymin/code (32) must stay resident; R3's 56-VGPR allocation
// spilled and serialized every B load at L2 latency.
__global__ __launch_bounds__(256, 2) void monn_mfma_kernel(
    const float* __restrict__ x,
    const _Float16* __restrict__ w_hi,
    const _Float16* __restrict__ w_lo,
    const float* __restrict__ t,
    float* __restrict__ y,
    float* __restrict__ A) {

    const int lane = threadIdx.x & 63;
    const int wave = blockIdx.x * 4 + (threadIdx.x >> 6);
    const long base = (long)wave * 64;
    if (base >= NS) return;           // whole-wave exit

    const int m = lane & 15;
    const int q = lane >> 4;

    // --- Load 64 x rows (16 float4s, issued up-front) and split to fp16 hi/lo ---
    // Fragment layout (measured, m89): A[row = lane&15][k = (lane>>4)*8 + j]
    float4 xv[4][2][2];
#pragma unroll
    for (int rt = 0; rt < 4; ++rt) {
        long row = base + rt * 16 + m;
        if (row >= NS) row = NS - 1;          // tail clamp; stores guarded below
        const float* xp = x + row * NF;
#pragma unroll
        for (int s = 0; s < 2; ++s) {
            const int k0 = s * 32 + q * 8;
            xv[rt][s][0] = *reinterpret_cast<const float4*>(xp + k0);
            xv[rt][s][1] = *reinterpret_cast<const float4*>(xp + k0 + 4);
        }
    }
    half8 Ah[4][2], Al[4][2];
#pragma unroll
    for (int rt = 0; rt < 4; ++rt)
#pragma unroll
        for (int s = 0; s < 2; ++s) {
            const float f[8] = {xv[rt][s][0].x, xv[rt][s][0].y, xv[rt][s][0].z, xv[rt][s][0].w,
                                xv[rt][s][1].x, xv[rt][s][1].y, xv[rt][s][1].z, xv[rt][s][1].w};
#pragma unroll
            for (int j = 0; j < 8; ++j) {
                _Float16 h = (_Float16)f[j];
                Ah[rt][s][j] = h;
                Al[rt][s][j] = (_Float16)(f[j] - (float)h);
            }
        }

    float    ymin[4][4];
    unsigned code[4][4];
#pragma unroll
    for (int rt = 0; rt < 4; ++rt)
#pragma unroll
        for (int j = 0; j < 4; ++j) { ymin[rt][j] = INFINITY; code[rt][j] = 0; }

    for (int g = 0; g < KG; ++g) {
        // t for this group's cols: issued here, consumed after 96 MFMAs (latency hidden)
        float tv[4];
#pragma unroll
        for (int c = 0; c < 4; ++c) tv[c] = t[g * HKC + c * 16 + m];

        f32x4 acc[4][4];
#pragma unroll
        for (int rt = 0; rt < 4; ++rt)
#pragma unroll
            for (int c = 0; c < 4; ++c) acc[rt][c] = (f32x4){0.f, 0.f, 0.f, 0.f};

#pragma unroll
        for (int s = 0; s < 2; ++s) {
            // batch all 8 B loads for this (g,s) -> single vmcnt drain per 48 MFMAs
            half8 Bh[4], Bl[4];
#pragma unroll
            for (int c = 0; c < 4; ++c) {
                const size_t off = (size_t)(g * HKC + c * 16 + m) * NF + s * 32 + q * 8;
                Bh[c] = *reinterpret_cast<const half8*>(w_hi + off);
                Bl[c] = *reinterpret_cast<const half8*>(w_lo + off);
            }
#pragma unroll
            for (int c = 0; c < 4; ++c)
#pragma unroll
                for (int rt = 0; rt < 4; ++rt) {
                    acc[rt][c] = __builtin_amdgcn_mfma_f32_16x16x32_f16(Ah[rt][s], Bh[c], acc[rt][c], 0, 0, 0);
                    acc[rt][c] = __builtin_amdgcn_mfma_f32_16x16x32_f16(Al[rt][s], Bh[c], acc[rt][c], 0, 0, 0);
                    acc[rt][c] = __builtin_amdgcn_mfma_f32_16x16x32_f16(Ah[rt][s], Bl[c], acc[rt][c], 0, 0, 0);
                }
        }

        // --- epilogue: per row argmax over 64 cols (bias added here), running min ---
#pragma unroll
        for (int rt = 0; rt < 4; ++rt)
#pragma unroll
            for (int j = 0; j < 4; ++j) {
                const float b0 = acc[rt][0][j] + tv[0];
                const float b1 = acc[rt][1][j] + tv[1];
                const float b2 = acc[rt][2][j] + tv[2];
                const float b3 = acc[rt][3][j] + tv[3];
                const float vmax = row_max16(fmaxf(fmaxf(b0, b1), fmaxf(b2, b3)));
                // smallest matching h in-lane (descending c keeps first occurrence),
                // then 16-lane min -> jnp.argmax first-index semantics
                unsigned h = 0x7FFFFFFFu;
                h = (b3 == vmax) ? (unsigned)(48 + m) : h;
                h = (b2 == vmax) ? (unsigned)(32 + m) : h;
                h = (b1 == vmax) ? (unsigned)(16 + m) : h;
                h = (b0 == vmax) ? (unsigned)(m)      : h;
                h = row_min16_u(h);
                // running min over groups: strict < keeps first (lowest g)
                if (vmax < ymin[rt][j]) { ymin[rt][j] = vmax; code[rt][j] = (unsigned)(g * HKC) + h; }
            }
    }

    // one lane per row-of-16 writes y and bumps the histogram
    if (m == 0) {
#pragma unroll
        for (int rt = 0; rt < 4; ++rt)
#pragma unroll
            for (int j = 0; j < 4; ++j) {
                const long row = base + rt * 16 + q * 4 + j;
                if (row < NS) {
                    y[row] = ymin[rt][j];
                    atomicAdd(&A[code[rt][j]], 1.0f);  // device-scope by default
                }
            }
    }
}

extern "C" void kernel_launch(void* const* d_in, const int* in_sizes, int n_in,
                              void* d_out, int out_size, void* d_ws, size_t ws_size,
                              hipStream_t stream) {
    const float* x = (const float*)d_in[0];  // [NS, NF]
    const float* z = (const float*)d_in[1];  // [KG, HKC, NF]
    const float* t = (const float*)d_in[2];  // [KG, HKC]

    float* y = (float*)d_out;        // [NS]
    float* A = (float*)d_out + NS;   // [KG*HKC]

    _Float16* w_hi = (_Float16*)d_ws;                 // 64 KB
    _Float16* w_lo = w_hi + (size_t)KG * HKC * NF;    // 64 KB

    const int prep_elems = KG * HKC * NF;
    prep_kernel<<<(prep_elems + 255) / 256, 256, 0, stream>>>(z, w_hi, w_lo, A);

    const int waves  = (NS + 63) / 64;          // 7813
    const int blocks = (waves + 3) / 4;         // 1954
    monn_mfma_kernel<<<blocks, 256, 0, stream>>>(x, w_hi, w_lo, t, y, A);
}

// Round 5
// 343.803 us; speedup vs baseline: 1.9468x; 1.8271x over previous
//
#include <hip/hip_runtime.h>
#include <math.h>

// Problem constants: N=500000, NFEAT=64, K=8, HK=64
constexpr int NS    = 500000;
constexpr int NF    = 64;
constexpr int KG    = 8;
constexpr int HKC   = 64;
constexpr int NCELL = KG * HKC;           // 512 histogram cells
constexpr int NBLK  = (NS + 255) / 256;   // 1954 phase-A blocks (256 rows each)

typedef __attribute__((ext_vector_type(8))) _Float16 half8;
typedef __attribute__((ext_vector_type(4))) float f32x4;

// ---- DPP row_ror helpers (rotate within each 16-lane row; VALU pipe, no LDS) ----
template <int CTRL>
__device__ __forceinline__ float row_ror_f(float v) {
    int i = __float_as_int(v);
    int r = __builtin_amdgcn_update_dpp(i, i, CTRL, 0xF, 0xF, false);
    return __int_as_float(r);
}
template <int CTRL>
__device__ __forceinline__ unsigned row_ror_u(unsigned v) {
    return (unsigned)__builtin_amdgcn_update_dpp((int)v, (int)v, CTRL, 0xF, 0xF, false);
}
__device__ __forceinline__ float row_max16(float v) {
    v = fmaxf(v, row_ror_f<0x121>(v));  // row_ror:1
    v = fmaxf(v, row_ror_f<0x122>(v));  // row_ror:2
    v = fmaxf(v, row_ror_f<0x124>(v));  // row_ror:4
    v = fmaxf(v, row_ror_f<0x128>(v));  // row_ror:8
    return v;
}
__device__ __forceinline__ unsigned row_min16_u(unsigned v) {
    v = min(v, row_ror_u<0x121>(v));
    v = min(v, row_ror_u<0x122>(v));
    v = min(v, row_ror_u<0x124>(v));
    v = min(v, row_ror_u<0x128>(v));
    return v;
}

// Kernel 1: w = exp(z) (fp32) split into fp16 hi/lo pair; zero the A region.
__global__ void prep_kernel(const float* __restrict__ z,
                            _Float16* __restrict__ w_hi,
                            _Float16* __restrict__ w_lo,
                            float* __restrict__ A) {
    int i = blockIdx.x * blockDim.x + threadIdx.x;
    if (i < KG * HKC * NF) {
        float w = expf(z[i]);
        _Float16 h = (_Float16)w;           // RNE
        w_hi[i] = h;
        w_lo[i] = (_Float16)(w - (float)h); // residual: ~2^-22 total pair error
    }
    if (i < NCELL) A[i] = 0.0f;
}

// Main kernel: one wave = 64 rows (4 MFMA row-tiles) x all 512 cols.
// PRIV=true: histogram into per-block LDS (ds_add_u32), flushed as plain
// coalesced stores to partial[NBLK][512] — NO global atomic RMW storm.
// (R2-R4 post-mortem: 500k memory-side fp32 atomics onto 32 cache lines
//  serialized to a ~500 us floor; WRITE_SIZE 17 MB was the fingerprint.)
template <bool PRIV>
__global__ __launch_bounds__(256, 2) void monn_mfma_kernel(
    const float* __restrict__ x,
    const _Float16* __restrict__ w_hi,
    const _Float16* __restrict__ w_lo,
    const float* __restrict__ t,
    float* __restrict__ y,
    float* __restrict__ dest) {   // PRIV ? partial buffer : global A

    __shared__ unsigned lhist[NCELL];
    if (PRIV) {
        for (int i = threadIdx.x; i < NCELL; i += 256) lhist[i] = 0u;
        __syncthreads();
    }

    const int lane = threadIdx.x & 63;
    const int wave = blockIdx.x * 4 + (threadIdx.x >> 6);
    const long base = (long)wave * 64;
    const int m = lane & 15;
    const int q = lane >> 4;

    if (base < NS) {   // predicated, not early-return: barriers stay uniform
        // --- Load 64 x rows and split to fp16 hi/lo fragments ---
        // A layout (measured, m89): A[row = lane&15][k = (lane>>4)*8 + j]
        float4 xv[4][2][2];
#pragma unroll
        for (int rt = 0; rt < 4; ++rt) {
            long row = base + rt * 16 + m;
            if (row >= NS) row = NS - 1;      // tail clamp; stores guarded below
            const float* xp = x + row * NF;
#pragma unroll
            for (int s = 0; s < 2; ++s) {
                const int k0 = s * 32 + q * 8;
                xv[rt][s][0] = *reinterpret_cast<const float4*>(xp + k0);
                xv[rt][s][1] = *reinterpret_cast<const float4*>(xp + k0 + 4);
            }
        }
        half8 Ah[4][2], Al[4][2];
#pragma unroll
        for (int rt = 0; rt < 4; ++rt)
#pragma unroll
            for (int s = 0; s < 2; ++s) {
                const float f[8] = {xv[rt][s][0].x, xv[rt][s][0].y, xv[rt][s][0].z, xv[rt][s][0].w,
                                    xv[rt][s][1].x, xv[rt][s][1].y, xv[rt][s][1].z, xv[rt][s][1].w};
#pragma unroll
                for (int j = 0; j < 8; ++j) {
                    _Float16 h = (_Float16)f[j];
                    Ah[rt][s][j] = h;
                    Al[rt][s][j] = (_Float16)(f[j] - (float)h);
                }
            }

        float    ymin[4][4];
        unsigned code[4][4];
#pragma unroll
        for (int rt = 0; rt < 4; ++rt)
#pragma unroll
            for (int j = 0; j < 4; ++j) { ymin[rt][j] = INFINITY; code[rt][j] = 0; }

        for (int g = 0; g < KG; ++g) {
            float tv[4];
#pragma unroll
            for (int c = 0; c < 4; ++c) tv[c] = t[g * HKC + c * 16 + m];

            f32x4 acc[4][4];
#pragma unroll
            for (int rt = 0; rt < 4; ++rt)
#pragma unroll
                for (int c = 0; c < 4; ++c) acc[rt][c] = (f32x4){0.f, 0.f, 0.f, 0.f};

#pragma unroll
            for (int s = 0; s < 2; ++s) {
                // batch all 8 B loads for this (g,s) -> one vmcnt drain per 48 MFMAs
                half8 Bh[4], Bl[4];
#pragma unroll
                for (int c = 0; c < 4; ++c) {
                    const size_t off = (size_t)(g * HKC + c * 16 + m) * NF + s * 32 + q * 8;
                    Bh[c] = *reinterpret_cast<const half8*>(w_hi + off);
                    Bl[c] = *reinterpret_cast<const half8*>(w_lo + off);
                }
#pragma unroll
                for (int c = 0; c < 4; ++c)
#pragma unroll
                    for (int rt = 0; rt < 4; ++rt) {
                        acc[rt][c] = __builtin_amdgcn_mfma_f32_16x16x32_f16(Ah[rt][s], Bh[c], acc[rt][c], 0, 0, 0);
                        acc[rt][c] = __builtin_amdgcn_mfma_f32_16x16x32_f16(Al[rt][s], Bh[c], acc[rt][c], 0, 0, 0);
                        acc[rt][c] = __builtin_amdgcn_mfma_f32_16x16x32_f16(Ah[rt][s], Bl[c], acc[rt][c], 0, 0, 0);
                    }
            }

            // --- epilogue: per-row argmax over 64 cols (bias added here), running min ---
#pragma unroll
            for (int rt = 0; rt < 4; ++rt)
#pragma unroll
                for (int j = 0; j < 4; ++j) {
                    const float b0 = acc[rt][0][j] + tv[0];
                    const float b1 = acc[rt][1][j] + tv[1];
                    const float b2 = acc[rt][2][j] + tv[2];
                    const float b3 = acc[rt][3][j] + tv[3];
                    const float vmax = row_max16(fmaxf(fmaxf(b0, b1), fmaxf(b2, b3)));
                    // smallest matching h in-lane (descending c keeps first occurrence),
                    // then 16-lane min -> jnp.argmax first-index semantics
                    unsigned h = 0x7FFFFFFFu;
                    h = (b3 == vmax) ? (unsigned)(48 + m) : h;
                    h = (b2 == vmax) ? (unsigned)(32 + m) : h;
                    h = (b1 == vmax) ? (unsigned)(16 + m) : h;
                    h = (b0 == vmax) ? (unsigned)(m)      : h;
                    h = row_min16_u(h);
                    // running min over groups: strict < keeps first (lowest g)
                    if (vmax < ymin[rt][j]) { ymin[rt][j] = vmax; code[rt][j] = (unsigned)(g * HKC) + h; }
                }
        }

        // one lane per row-of-16 writes y and bumps the (private) histogram
        if (m == 0) {
#pragma unroll
            for (int rt = 0; rt < 4; ++rt)
#pragma unroll
                for (int j = 0; j < 4; ++j) {
                    const long row = base + rt * 16 + q * 4 + j;
                    if (row < NS) {
                        y[row] = ymin[rt][j];
                        if (PRIV) atomicAdd(&lhist[code[rt][j]], 1u);      // LDS, banked
                        else      atomicAdd(&dest[code[rt][j]], 1.0f);     // fallback
                    }
                }
        }
    }

    if (PRIV) {
        __syncthreads();
        // plain coalesced stores of this block's 512-cell histogram
        float* p = dest + (size_t)blockIdx.x * NCELL;
        for (int i = threadIdx.x; i < NCELL; i += 256) p[i] = (float)lhist[i];
    }
}

// Phase B: A[c] = sum_b partial[b][c]. 64 blocks x 256 threads; 32 slices/cell.
// 16384 atomics onto 512 cells (32/cell) — negligible contention.
__global__ void reduce_kernel(const float* __restrict__ partial, float* __restrict__ A) {
    const int tid = blockIdx.x * blockDim.x + threadIdx.x;   // 0..16383
    const int c = tid & (NCELL - 1);
    const int s = tid >> 9;                                  // 0..31
    float sum = 0.0f;
    for (int b = s; b < NBLK; b += 32)                       // coalesced across lanes
        sum += partial[(size_t)b * NCELL + c];
    atomicAdd(&A[c], sum);
}

extern "C" void kernel_launch(void* const* d_in, const int* in_sizes, int n_in,
                              void* d_out, int out_size, void* d_ws, size_t ws_size,
                              hipStream_t stream) {
    const float* x = (const float*)d_in[0];  // [NS, NF]
    const float* z = (const float*)d_in[1];  // [KG, HKC, NF]
    const float* t = (const float*)d_in[2];  // [KG, HKC]

    float* y = (float*)d_out;        // [NS]
    float* A = (float*)d_out + NS;   // [NCELL]

    _Float16* w_hi = (_Float16*)d_ws;                          // 64 KB
    _Float16* w_lo = w_hi + (size_t)KG * HKC * NF;             // 64 KB
    float* partial = (float*)((char*)d_ws + 2 * sizeof(_Float16) * KG * HKC * NF);

    const size_t need = 2 * sizeof(_Float16) * KG * HKC * NF
                      + (size_t)NBLK * NCELL * sizeof(float);  // ~4.13 MB

    const int prep_elems = KG * HKC * NF;
    prep_kernel<<<(prep_elems + 255) / 256, 256, 0, stream>>>(z, w_hi, w_lo, A);

    if (ws_size >= need) {
        monn_mfma_kernel<true><<<NBLK, 256, 0, stream>>>(x, w_hi, w_lo, t, y, partial);
        reduce_kernel<<<64, 256, 0, stream>>>(partial, A);
    } else {
        monn_mfma_kernel<false><<<NBLK, 256, 0, stream>>>(x, w_hi, w_lo, t, y, A);
    }
}